// Round 4
// baseline (449.870 us; speedup 1.0000x reference)
//
#include <hip/hip_runtime.h>

#define Nn 384
#define Cc 128
#define DHh 32
#define NHh 4
#define NPOS (Nn*Nn)
#define LOG2E 1.4426950408889634f

typedef unsigned short ushort_t;
typedef __attribute__((ext_vector_type(8))) short bf16x8;
typedef __attribute__((ext_vector_type(4))) float f32x4;

__device__ __forceinline__ ushort_t f2bf(float f) {
  union { float f; unsigned int u; } v; v.f = f;
  unsigned int r = v.u + 0x7fffu + ((v.u >> 16) & 1u);   // RNE
  return (ushort_t)(r >> 16);
}
__device__ __forceinline__ ushort_t f2bf_ru(float f) {   // round-half-up (cheap)
  union { float f; unsigned int u; } v; v.f = f;
  return (ushort_t)((v.u + 0x8000u) >> 16);
}
// pack two positive floats to bf16x2 (round-half-up) via v_perm
__device__ __forceinline__ unsigned int pk2(float a, float b) {
  union { float f; unsigned int u; } ua, ub; ua.f = a; ub.f = b;
  return __builtin_amdgcn_perm(ub.u + 0x8000u, ua.u + 0x8000u, 0x07060302u);
}
__device__ __forceinline__ float bf2f(ushort_t u) {
  union { unsigned int u; float f; } v; v.u = ((unsigned int)u) << 16;
  return v.f;
}

// ---------------------------------------------------------------------------
// Kernel 0: wBt[512][128] bf16 = concat(wq,wk,wv,wg); q rows scaled by
// (1/sqrt(32))*log2e (exp2 softmax trick). woT[128][128] bf16 = wo cast.
// ---------------------------------------------------------------------------
__global__ __launch_bounds__(256) void k_wt(const float* __restrict__ wq,
    const float* __restrict__ wk, const float* __restrict__ wv,
    const float* __restrict__ wg, const float* __restrict__ wo,
    ushort_t* __restrict__ wBt, ushort_t* __restrict__ woT) {
  for (int rep = 0; rep < 4; ++rep) {
    int idx = blockIdx.x * 256 + threadIdx.x + rep * 20480;  // 80 blocks
    if (idx < 65536) {
      int c = idx >> 7, k = idx & 127;
      int mat = c >> 7, row = c & 127;
      const float* src;
      float scale = 1.0f;
      if (mat == 0)      { src = wq; scale = 0.17677669529663687f * LOG2E; }
      else if (mat == 1) { src = wk; }
      else if (mat == 2) { src = wv; }
      else               { src = wg; }
      wBt[idx] = f2bf(src[row * 128 + k] * scale);
    } else {
      int j = idx - 65536;
      woT[j] = f2bf(wo[j]);
    }
  }
}

// ---------------------------------------------------------------------------
// Kernel 1: LayerNorm (wave per position) -> xn bf16; triangle bias fp32 in
// NATURAL [h][q][k] layout (= [h][p]), pre-scaled by log2e.
// ---------------------------------------------------------------------------
__global__ __launch_bounds__(256) void k_ln(const float* __restrict__ x,
    const float* __restrict__ gamma, const float* __restrict__ beta,
    const float* __restrict__ wb, unsigned int* __restrict__ xnb,
    float* __restrict__ biasN) {
  int wid = threadIdx.x >> 6, lane = threadIdx.x & 63;
  int p = blockIdx.x * 4 + wid;
  size_t base = (size_t)p * Cc + lane * 2;
  float2 xv = *(const float2*)&x[base];
  float s = xv.x + xv.y;
  #pragma unroll
  for (int off = 1; off < 64; off <<= 1) s += __shfl_xor(s, off, 64);
  float mu = s * (1.0f / Cc);
  float d0 = xv.x - mu, d1 = xv.y - mu;
  float sq = d0 * d0 + d1 * d1;
  #pragma unroll
  for (int off = 1; off < 64; off <<= 1) sq += __shfl_xor(sq, off, 64);
  float rs = rsqrtf(sq * (1.0f / Cc) + 1e-5f);
  float2 g2 = *(const float2*)&gamma[lane * 2];
  float2 b2 = *(const float2*)&beta[lane * 2];
  float xn0 = d0 * rs * g2.x + b2.x;
  float xn1 = d1 * rs * g2.y + b2.y;
  unsigned int pack = (unsigned int)f2bf(xn0) | ((unsigned int)f2bf(xn1) << 16);
  xnb[(size_t)p * 64 + lane] = pack;
  #pragma unroll
  for (int h = 0; h < NHh; ++h) {
    float2 w2 = *(const float2*)&wb[h * Cc + lane * 2];
    float t = xn0 * w2.x + xn1 * w2.y;
    #pragma unroll
    for (int off = 1; off < 64; off <<= 1) t += __shfl_xor(t, off, 64);
    if (lane == 0) biasN[(size_t)h * NPOS + p] = t * LOG2E;
  }
}

// ---------------------------------------------------------------------------
// Kernel 2: projection GEMM via MFMA, looping all 8 n-chunks per block so the
// A-tile is staged and frag-loaded ONCE. Cs aliases Bs.
// ---------------------------------------------------------------------------
__global__ __launch_bounds__(256, 3) void k_proj(const ushort_t* __restrict__ xnb,
    const ushort_t* __restrict__ wBt, const float* __restrict__ bg,
    ushort_t* __restrict__ qkvg) {
  __shared__ __align__(16) char plds[34816 + 18432];
  ushort_t* As = (ushort_t*)plds;              // [128][136]
  ushort_t* Bs = (ushort_t*)(plds + 34816);    // [64][136]  (17408 B)
  ushort_t* Cs = (ushort_t*)(plds + 34816);    // [128][72]  (18432 B, alias)
  const int tid = threadIdx.x, lane = tid & 63, w = tid >> 6;
  const int q15 = lane & 15, quad = lane >> 4;
  const int m0 = blockIdx.x * 128;

  #pragma unroll
  for (int r = 0; r < 8; ++r) {
    int idx = tid + 256 * r;
    int row = idx >> 4, seg = idx & 15;
    *(uint4*)&As[row * 136 + seg * 8] =
        *(const uint4*)&xnb[(size_t)(m0 + row) * 128 + seg * 8];
  }
  __syncthreads();
  bf16x8 af[4][2];
  #pragma unroll
  for (int kk = 0; kk < 4; ++kk)
    #pragma unroll
    for (int mi = 0; mi < 2; ++mi)
      af[kk][mi] = *(const bf16x8*)&As[(w * 32 + mi * 16 + q15) * 136 +
                                       kk * 32 + quad * 8];

  for (int nb = 0; nb < 8; ++nb) {
    #pragma unroll
    for (int r = 0; r < 4; ++r) {
      int idx = tid + 256 * r;
      int row = idx >> 4, seg = idx & 15;
      *(uint4*)&Bs[row * 136 + seg * 8] =
          *(const uint4*)&wBt[(size_t)(nb * 64 + row) * 128 + seg * 8];
    }
    __syncthreads();

    f32x4 acc[2][4];
    #pragma unroll
    for (int mi = 0; mi < 2; ++mi)
      #pragma unroll
      for (int ni = 0; ni < 4; ++ni) {
        float init = 0.0f;
        if (nb >= 6) init = bg[(nb & 1) * 64 + ni * 16 + q15];
        acc[mi][ni][0] = init; acc[mi][ni][1] = init;
        acc[mi][ni][2] = init; acc[mi][ni][3] = init;
      }
    #pragma unroll
    for (int kk = 0; kk < 4; ++kk) {
      bf16x8 bf[4];
      #pragma unroll
      for (int ni = 0; ni < 4; ++ni)
        bf[ni] = *(const bf16x8*)&Bs[(ni * 16 + q15) * 136 + kk * 32 + quad * 8];
      #pragma unroll
      for (int mi = 0; mi < 2; ++mi)
        #pragma unroll
        for (int ni = 0; ni < 4; ++ni)
          acc[mi][ni] = __builtin_amdgcn_mfma_f32_16x16x32_bf16(
              af[kk][mi], bf[ni], acc[mi][ni], 0, 0, 0);
    }
    __syncthreads();                 // Bs frag reads done (Cs aliases Bs)
    #pragma unroll
    for (int mi = 0; mi < 2; ++mi)
      #pragma unroll
      for (int ni = 0; ni < 4; ++ni)
        #pragma unroll
        for (int r = 0; r < 4; ++r) {
          int rowL = w * 32 + mi * 16 + quad * 4 + r;
          Cs[rowL * 72 + ni * 16 + q15] = f2bf(acc[mi][ni][r]);
        }
    __syncthreads();
    const int mat = nb >> 1;
    #pragma unroll
    for (int r = 0; r < 4; ++r) {
      int idx = tid + 256 * r;
      int row = idx >> 3, seg = idx & 7;
      int cl = (nb & 1) * 64 + seg * 8;
      int hh = cl >> 5, dd = cl & 31;
      uint4 v = *(const uint4*)&Cs[row * 72 + seg * 8];
      *(uint4*)&qkvg[(size_t)mat * (NHh * (size_t)NPOS * 32) +
                     (size_t)hh * ((size_t)NPOS * 32) +
                     (size_t)(m0 + row) * 32 + dd] = v;
    }
    __syncthreads();                 // Cs reads done before next Bs stage
  }
}

// ---------------------------------------------------------------------------
// Kernel 3: MFMA flash attention, S-TRANSPOSED formulation.
// T = K·Q^T so the C-fragment fast axis is k: bias/mask C-init loads are
// lane-contiguous float4 over k; P-pack writes are b64; softmax sum = 2 shfl.
// Per-wave partial row-sums; single cross-wave reduce in epilogue (no-max
// softmax). LDS 53760 B -> 3 blocks/CU, no aliasing in main loop.
// ---------------------------------------------------------------------------
__global__ __launch_bounds__(256, 3) void k_attn(const ushort_t* __restrict__ qkvg,
    const float* __restrict__ biasN, const float* __restrict__ mask,
    ushort_t* __restrict__ o_ws) {
  __shared__ __align__(16) char lds[53760];
  ushort_t* Ks = (ushort_t*)lds;               // [128][40] (10240 B), also Q
  ushort_t* Vt = (ushort_t*)(lds + 10240);     // [32][136] (8704 B)
  ushort_t* Pt = (ushort_t*)(lds + 18944);     // [128 q][136 k] (34816 B)
  float*  lsWS = (float*)(lds + 18944);        // [4][128] (alias Pt, epilogue)

  const int tid = threadIdx.x, lane = tid & 63, w = tid >> 6;
  const int q15 = lane & 15, quad = lane >> 4;
  const int h  = blockIdx.x / 3;
  const int qt = blockIdx.x % 3;
  const int i  = blockIdx.y;
  const int q0 = qt * 128;

  const ushort_t* q_all = qkvg;
  const ushort_t* k_all = qkvg + (size_t)1 * NHh * NPOS * 32;
  const ushort_t* v_all = qkvg + (size_t)2 * NHh * NPOS * 32;
  const ushort_t* g_all = qkvg + (size_t)3 * NHh * NPOS * 32;
  const size_t hbase = ((size_t)h * NPOS + (size_t)i * Nn) * 32;
  const float* brow = biasN + (size_t)h * NPOS;

  // ---- stage Q tile, pull B-operand frags (all 8 n-tiles) to registers ----
  #pragma unroll
  for (int r = 0; r < 2; ++r) {
    int idx = tid + 256 * r;
    int row = idx >> 2, seg = idx & 3;
    *(uint4*)&Ks[row * 40 + seg * 8] =
        *(const uint4*)&q_all[hbase + (size_t)(q0 + row) * 32 + seg * 8];
  }
  __syncthreads();
  bf16x8 qf[8];
  #pragma unroll
  for (int ni = 0; ni < 8; ++ni)
    qf[ni] = *(const bf16x8*)&Ks[(ni * 16 + q15) * 40 + quad * 8];

  f32x4 oacc[2][2];
  #pragma unroll
  for (int mi = 0; mi < 2; ++mi)
    #pragma unroll
    for (int ni = 0; ni < 2; ++ni) {
      oacc[mi][ni][0] = 0.f; oacc[mi][ni][1] = 0.f;
      oacc[mi][ni][2] = 0.f; oacc[mi][ni][3] = 0.f;
    }
  float lsum[8];
  #pragma unroll
  for (int ni = 0; ni < 8; ++ni) lsum[ni] = 0.f;

  for (int ch = 0; ch < 3; ++ch) {
    const int kbase = ch * 128;
    __syncthreads();   // qf reads (ch0) / prev Pt+Vt reads complete
    #pragma unroll
    for (int r = 0; r < 2; ++r) {
      int idx = tid + 256 * r;
      int row = idx >> 2, seg = idx & 3;
      *(uint4*)&Ks[row * 40 + seg * 8] =
          *(const uint4*)&k_all[hbase + (size_t)(kbase + row) * 32 + seg * 8];
    }
    #pragma unroll
    for (int r = 0; r < 8; ++r) {
      int idx = tid + 256 * r;
      int pos = idx >> 4, dp = idx & 15;
      unsigned int val = *(const unsigned int*)
          &v_all[hbase + (size_t)(kbase + pos) * 32 + dp * 2];
      Vt[(dp * 2 + 0) * 136 + pos] = (ushort_t)(val & 0xffff);
      Vt[(dp * 2 + 1) * 136 + pos] = (ushort_t)(val >> 16);
    }
    __syncthreads();

    // mask bias per mi (k-contiguous float4, broadcast across q15)
    f32x4 mb4[2];
    #pragma unroll
    for (int mi = 0; mi < 2; ++mi) {
      float4 mk = *(const float4*)&mask[i * Nn + kbase + w * 32 + mi * 16 + quad * 4];
      mb4[mi][0] = (mk.x - 1.0f) * (1e9f * LOG2E);
      mb4[mi][1] = (mk.y - 1.0f) * (1e9f * LOG2E);
      mb4[mi][2] = (mk.z - 1.0f) * (1e9f * LOG2E);
      mb4[mi][3] = (mk.w - 1.0f) * (1e9f * LOG2E);
    }
    bf16x8 kf[2];
    #pragma unroll
    for (int mi = 0; mi < 2; ++mi)
      kf[mi] = *(const bf16x8*)&Ks[(w * 32 + mi * 16 + q15) * 40 + quad * 8];

    // two n-groups of 4 q-tiles to cap sf register pressure
    #pragma unroll
    for (int nh = 0; nh < 2; ++nh) {
      f32x4 sf[2][4];
      #pragma unroll
      for (int ng = 0; ng < 4; ++ng) {
        int q = q0 + (nh * 4 + ng) * 16 + q15;
        #pragma unroll
        for (int mi = 0; mi < 2; ++mi) {
          float4 b4 = *(const float4*)
              &brow[(size_t)q * Nn + kbase + w * 32 + mi * 16 + quad * 4];
          sf[mi][ng][0] = b4.x + mb4[mi][0];
          sf[mi][ng][1] = b4.y + mb4[mi][1];
          sf[mi][ng][2] = b4.z + mb4[mi][2];
          sf[mi][ng][3] = b4.w + mb4[mi][3];
        }
      }
      #pragma unroll
      for (int ng = 0; ng < 4; ++ng)
        #pragma unroll
        for (int mi = 0; mi < 2; ++mi)
          sf[mi][ng] = __builtin_amdgcn_mfma_f32_16x16x32_bf16(
              kf[mi], qf[nh * 4 + ng], sf[mi][ng], 0, 0, 0);
      #pragma unroll
      for (int ng = 0; ng < 4; ++ng) {
        float t = 0.f;
        #pragma unroll
        for (int mi = 0; mi < 2; ++mi)
          #pragma unroll
          for (int r = 0; r < 4; ++r) {
            float e = exp2f(sf[mi][ng][r]);
            sf[mi][ng][r] = e;
            t += e;
          }
        t += __shfl_xor(t, 16, 64);
        t += __shfl_xor(t, 32, 64);
        lsum[nh * 4 + ng] += t;
        int q = (nh * 4 + ng) * 16 + q15;
        #pragma unroll
        for (int mi = 0; mi < 2; ++mi) {
          uint2 uu;
          uu.x = pk2(sf[mi][ng][0], sf[mi][ng][1]);
          uu.y = pk2(sf[mi][ng][2], sf[mi][ng][3]);
          *(uint2*)&Pt[q * 136 + w * 32 + mi * 16 + quad * 4] = uu;
        }
      }
    }
    __syncthreads();   // all Pt writes visible
    // O += P V  (each wave owns q rows [w*32, w*32+32))
    #pragma unroll
    for (int kk = 0; kk < 4; ++kk) {
      bf16x8 pa[2], vb[2];
      #pragma unroll
      for (int mi = 0; mi < 2; ++mi)
        pa[mi] = *(const bf16x8*)&Pt[(w * 32 + mi * 16 + q15) * 136 +
                                     kk * 32 + quad * 8];
      #pragma unroll
      for (int ni = 0; ni < 2; ++ni)
        vb[ni] = *(const bf16x8*)&Vt[(ni * 16 + q15) * 136 + kk * 32 + quad * 8];
      #pragma unroll
      for (int mi = 0; mi < 2; ++mi)
        #pragma unroll
        for (int ni = 0; ni < 2; ++ni)
          oacc[mi][ni] = __builtin_amdgcn_mfma_f32_16x16x32_bf16(
              pa[mi], vb[ni], oacc[mi][ni], 0, 0, 0);
    }
  }

  // ---- epilogue: cross-wave lsum reduce, normalize, gate, store bf16 ----
  __syncthreads();                   // Pt reads done (lsWS aliases Pt)
  if (quad == 0) {
    #pragma unroll
    for (int ni = 0; ni < 8; ++ni)
      lsWS[w * 128 + ni * 16 + q15] = lsum[ni];
  }
  __syncthreads();
  if (tid < 128) {
    float t = lsWS[tid] + lsWS[128 + tid] + lsWS[256 + tid] + lsWS[384 + tid];
    lsWS[tid] = 1.0f / t;
  }
  __syncthreads();
  #pragma unroll
  for (int mi = 0; mi < 2; ++mi) {
    float4 iv = *(const float4*)&lsWS[w * 32 + mi * 16 + quad * 4];
    #pragma unroll
    for (int ni = 0; ni < 2; ++ni)
      #pragma unroll
      for (int r = 0; r < 4; ++r) {
        int posg = i * Nn + q0 + w * 32 + mi * 16 + quad * 4 + r;
        int d = ni * 16 + q15;
        float gpre = bf2f(g_all[((size_t)h * NPOS + posg) * 32 + d]);
        float gate = 1.0f / (1.0f + __expf(-gpre));
        float invr = (r == 0) ? iv.x : (r == 1) ? iv.y : (r == 2) ? iv.z : iv.w;
        o_ws[(size_t)posg * Cc + h * DHh + d] =
            f2bf_ru(oacc[mi][ni][r] * invr * gate);
      }
  }
}

// ---------------------------------------------------------------------------
// Kernel 4: out = o_gated @ wo^T + bo via bf16 MFMA. M=128/block, N=128, K=128.
// ---------------------------------------------------------------------------
__global__ __launch_bounds__(256, 2) void k_out(const ushort_t* __restrict__ o_ws,
    const ushort_t* __restrict__ woT, const float* __restrict__ bo,
    float* __restrict__ out) {
  __shared__ ushort_t As[128 * 136];
  __shared__ ushort_t Bs[128 * 136];
  const int tid = threadIdx.x, lane = tid & 63, w = tid >> 6;
  const int q15 = lane & 15, quad = lane >> 4;
  const size_t m0 = (size_t)blockIdx.x * 128;

  #pragma unroll
  for (int r = 0; r < 8; ++r) {
    int idx = tid + 256 * r;
    int row = idx >> 4, seg = idx & 15;
    *(uint4*)&As[row * 136 + seg * 8] =
        *(const uint4*)&o_ws[(m0 + row) * 128 + seg * 8];
    *(uint4*)&Bs[row * 136 + seg * 8] =
        *(const uint4*)&woT[(size_t)row * 128 + seg * 8];
  }
  __syncthreads();

  f32x4 acc[2][8];
  #pragma unroll
  for (int mi = 0; mi < 2; ++mi)
    #pragma unroll
    for (int ni = 0; ni < 8; ++ni) {
      acc[mi][ni][0] = 0.f; acc[mi][ni][1] = 0.f;
      acc[mi][ni][2] = 0.f; acc[mi][ni][3] = 0.f;
    }
  #pragma unroll
  for (int kk = 0; kk < 4; ++kk) {
    bf16x8 a_[2];
    #pragma unroll
    for (int mi = 0; mi < 2; ++mi)
      a_[mi] = *(const bf16x8*)&As[(w * 32 + mi * 16 + q15) * 136 +
                                   kk * 32 + quad * 8];
    #pragma unroll
    for (int ni = 0; ni < 8; ++ni) {
      bf16x8 b_ = *(const bf16x8*)&Bs[(ni * 16 + q15) * 136 + kk * 32 + quad * 8];
      #pragma unroll
      for (int mi = 0; mi < 2; ++mi)
        acc[mi][ni] = __builtin_amdgcn_mfma_f32_16x16x32_bf16(
            a_[mi], b_, acc[mi][ni], 0, 0, 0);
    }
  }
  #pragma unroll
  for (int ni = 0; ni < 8; ++ni) {
    float bov = bo[ni * 16 + q15];
    #pragma unroll
    for (int mi = 0; mi < 2; ++mi)
      #pragma unroll
      for (int r = 0; r < 4; ++r) {
        int rowL = w * 32 + mi * 16 + quad * 4 + r;
        out[(m0 + rowL) * Cc + ni * 16 + q15] = acc[mi][ni][r] + bov;
      }
  }
}

// ---------------------------------------------------------------------------
extern "C" void kernel_launch(void* const* d_in, const int* in_sizes, int n_in,
                              void* d_out, int out_size, void* d_ws, size_t ws_size,
                              hipStream_t stream) {
  const float* x     = (const float*)d_in[0];
  const float* mask  = (const float*)d_in[1];
  const float* gamma = (const float*)d_in[2];
  const float* beta  = (const float*)d_in[3];
  const float* wb    = (const float*)d_in[4];
  const float* wq    = (const float*)d_in[5];
  const float* wk    = (const float*)d_in[6];
  const float* wv    = (const float*)d_in[7];
  const float* wg    = (const float*)d_in[8];
  const float* bg    = (const float*)d_in[9];
  const float* wo    = (const float*)d_in[10];
  const float* bo    = (const float*)d_in[11];
  float* out = (float*)d_out;

  char* ws = (char*)d_ws;
  ushort_t* xnb   = (ushort_t*)ws;                         // also o_ws (reused)
  ushort_t* qkvg  = (ushort_t*)(ws + (size_t)NPOS * 128 * 2);
  float*    biasN = (float*)(ws + (size_t)NPOS * 128 * 2
                                + (size_t)4 * NHh * NPOS * 32 * 2);
  ushort_t* wBt   = (ushort_t*)((char*)biasN + (size_t)NHh * NPOS * 4);
  ushort_t* woT   = wBt + 65536;
  ushort_t* o_ws  = xnb;   // xnb is dead after k_proj

  hipLaunchKernelGGL(k_wt, dim3(80), dim3(256), 0, stream,
                     wq, wk, wv, wg, wo, wBt, woT);
  hipLaunchKernelGGL(k_ln, dim3(NPOS / 4), dim3(256), 0, stream,
                     x, gamma, beta, wb, (unsigned int*)xnb, biasN);
  hipLaunchKernelGGL(k_proj, dim3(NPOS / 128), dim3(256), 0, stream,
                     xnb, wBt, bg, qkvg);
  hipLaunchKernelGGL(k_attn, dim3(12, Nn), dim3(256), 0, stream,
                     qkvg, biasN, mask, o_ws);
  hipLaunchKernelGGL(k_out, dim3(NPOS / 128), dim3(256), 0, stream,
                     o_ws, woT, bo, out);
}